// Round 7
// baseline (236.604 us; speedup 1.0000x reference)
//
#include <hip/hip_runtime.h>
#include <stdint.h>

typedef unsigned short u16;
typedef short bf16x8 __attribute__((ext_vector_type(8)));
typedef float f32x4 __attribute__((ext_vector_type(4)));

#define S_ 2048
#define HID_ 1024
#define H_ 16
#define D_ 64

#define LOG2E 1.4426950408889634f
#define SCALE_LOG2 0.18033688011112042f   /* 0.125 * log2(e) */
#define MAXC_LOG2 11.541560327111707f     /* 8 * log2(e) */

__device__ __forceinline__ u16 f2bf(float f) {
  uint32_t x = __builtin_bit_cast(uint32_t, f);
  uint32_t r = (x + 0x7fffu + ((x >> 16) & 1u)) >> 16;
  return (u16)r;
}
__device__ __forceinline__ uint32_t packbf2(float a, float b) {
  return (uint32_t)f2bf(a) | ((uint32_t)f2bf(b) << 16);
}
// truncating pack: low16 = bf16(a), high16 = bf16(b), one v_perm_b32
__device__ __forceinline__ uint32_t permpack(float a, float b) {
  return __builtin_amdgcn_perm(__builtin_bit_cast(uint32_t, b),
                               __builtin_bit_cast(uint32_t, a), 0x07060302u);
}

__device__ __forceinline__ void gl2lds16(const void* g, void* l) {
  __builtin_amdgcn_global_load_lds(
      (const __attribute__((address_space(1))) unsigned int*)g,
      (__attribute__((address_space(3))) unsigned int*)l, 16, 0, 0);
}

// ------------- prep: converts + RoPE tables + mask2, one kernel -------------
#define NX_ (1 << 20)
#define NW_ (1 << 18)
#define NROPE_ 65536
__global__ void prep_kernel(const float* __restrict__ X, const float* __restrict__ Wq,
                            const float* __restrict__ Wk, const float* __restrict__ Wv,
                            const float* __restrict__ mask, u16* __restrict__ Xb,
                            u16* __restrict__ Wqb, u16* __restrict__ Wkb,
                            u16* __restrict__ Wvb, float* __restrict__ cos_t,
                            float* __restrict__ sin_t, float* __restrict__ mask2) {
  int i = blockIdx.x * 256 + threadIdx.x;
  if (i < NX_ + 3 * NW_) {
    const float* src;
    u16* dst;
    int off;
    if (i < NX_) {
      src = X; dst = Xb; off = i;
    } else if (i < NX_ + NW_) {
      src = Wq; dst = Wqb; off = i - NX_;
    } else if (i < NX_ + 2 * NW_) {
      src = Wk; dst = Wkb; off = i - NX_ - NW_;
    } else {
      src = Wv; dst = Wvb; off = i - NX_ - 2 * NW_;
    }
    float4 v = ((const float4*)src)[off];
    uint2 packed;
    packed.x = packbf2(v.x, v.y);
    packed.y = packbf2(v.z, v.w);
    ((uint2*)dst)[off] = packed;
  } else if (i < NX_ + 3 * NW_ + NROPE_) {
    int t = i - (NX_ + 3 * NW_);  // 65536 = 2048*32
    int s = t >> 5, j = t & 31;
    float invf = powf(10000.0f, -(float)j * (1.0f / 32.0f));
    float ang = (float)s * invf;
    cos_t[t] = cosf(ang);
    sin_t[t] = sinf(ang);
  } else {
    int t = i - (NX_ + 3 * NW_ + NROPE_);  // 4096 = 2*2048
    mask2[t] = fmaf(mask[t], LOG2E, -MAXC_LOG2);
  }
}

// ---------------- Fused QKV GEMM (R6 proven): one block, Q+K+V for a 128x128 tile ----------------
// grid (8, 32) = 256 blocks = 1/CU, zero dispatch tail. 512 threads (8 waves 2m x 4n).
// A staged ONCE per K-step, shared by all 3 B matrices. LDS 128 KB dbuf,
// stage-before-compute, 1 barrier/K-step.
__global__ __launch_bounds__(512, 2) void qkv_gemm_kernel(
    const u16* __restrict__ X, const u16* __restrict__ Wq, const u16* __restrict__ Wk,
    const u16* __restrict__ Wv, const float* __restrict__ cos_t,
    const float* __restrict__ sin_t, u16* __restrict__ Q, u16* __restrict__ K,
    u16* __restrict__ Vt) {
  __shared__ char smem[131072];
  int tid = threadIdx.x;
  int lane = tid & 63, wave = tid >> 6;
  int wm = wave >> 2, wn = wave & 3;
  int quad = lane >> 4, l16 = lane & 15;
  int nbase = blockIdx.x * 128;
  int mbase = blockIdx.y * 128;

#define STAGE_ALL(k0, buf)                                                        \
  {                                                                               \
    _Pragma("unroll") for (int it = 0; it < 8; ++it) {                            \
      int j = (it & 1) * 512 + tid;                                               \
      int r = j >> 3, gs = j & 7, gsrc = gs ^ (r & 7);                            \
      const u16* src; int rb;                                                     \
      if ((it >> 1) == 0)      { src = X;  rb = mbase + r; }                      \
      else if ((it >> 1) == 1) { src = Wq; rb = nbase + r; }                      \
      else if ((it >> 1) == 2) { src = Wk; rb = nbase + r; }                      \
      else                     { src = Wv; rb = nbase + r; }                      \
      gl2lds16(src + (size_t)rb * HID_ + (k0) + gsrc * 8,                         \
               (buf) + (it >> 1) * 16384 + j * 16);                               \
    }                                                                             \
  }

  STAGE_ALL(0, smem)  // tile 0 -> buf 0

  f32x4 acc[3][4][2] = {};  // [which][i4 m-block][j2 n-pair]

  for (int kk = 0; kk < 16; ++kk) {
    const char* buf = smem + (kk & 1) * 65536;
    __syncthreads();  // staging of tile kk complete

    if (kk < 15)  // stage tile kk+1 into other buffer (its reads finished pre-barrier)
      STAGE_ALL((kk + 1) * 64, smem + ((kk + 1) & 1) * 65536)

#pragma unroll
    for (int kh = 0; kh < 2; ++kh) {
      bf16x8 afrag[4];
#pragma unroll
      for (int i4 = 0; i4 < 4; ++i4) {
        int r = wm * 64 + i4 * 16 + l16;
        int L = r * 8 + ((kh * 4 + quad) ^ (r & 7));
        afrag[i4] = *(const bf16x8*)(buf + L * 16);
      }
#pragma unroll
      for (int w = 0; w < 3; ++w) {
        const char* Bs = buf + 16384 + w * 16384;
        bf16x8 bfrag[2];
#pragma unroll
        for (int j2 = 0; j2 < 2; ++j2) {
          int r = (wn >> 1) * 64 + (wn & 1) * 16 + j2 * 32 + l16;
          int L = r * 8 + ((kh * 4 + quad) ^ (r & 7));
          bfrag[j2] = *(const bf16x8*)(Bs + L * 16);
        }
        if (w == 2) {
#pragma unroll
          for (int i4 = 0; i4 < 4; ++i4)
#pragma unroll
            for (int j2 = 0; j2 < 2; ++j2)
              acc[2][i4][j2] = __builtin_amdgcn_mfma_f32_16x16x32_bf16(
                  afrag[i4], bfrag[j2], acc[2][i4][j2], 0, 0, 0);
        } else if (w == 1) {
#pragma unroll
          for (int i4 = 0; i4 < 4; ++i4)
#pragma unroll
            for (int j2 = 0; j2 < 2; ++j2)
              acc[1][i4][j2] = __builtin_amdgcn_mfma_f32_16x16x32_bf16(
                  bfrag[j2], afrag[i4], acc[1][i4][j2], 0, 0, 0);
        } else {
#pragma unroll
          for (int i4 = 0; i4 < 4; ++i4)
#pragma unroll
            for (int j2 = 0; j2 < 2; ++j2)
              acc[0][i4][j2] = __builtin_amdgcn_mfma_f32_16x16x32_bf16(
                  bfrag[j2], afrag[i4], acc[0][i4][j2], 0, 0, 0);
        }
      }
    }
  }
#undef STAGE_ALL

  // ---- V epilogue (w=2, non-swapped): C row = m (quad*4+reg), col = n (l16) ----
#pragma unroll
  for (int i4 = 0; i4 < 4; ++i4)
#pragma unroll
    for (int j2 = 0; j2 < 2; ++j2) {
      int m = mbase + wm * 64 + i4 * 16 + quad * 4;
      int n = nbase + (wn >> 1) * 64 + (wn & 1) * 16 + j2 * 32 + l16;
      int b = m >> 11, s0 = m & 2047;
      int h = n >> 6, d = n & 63;
      uint2 pk;
      pk.x = packbf2(acc[2][i4][j2][0], acc[2][i4][j2][1]);
      pk.y = packbf2(acc[2][i4][j2][2], acc[2][i4][j2][3]);
      *(uint2*)(Vt + (((size_t)(b * H_ + h)) * D_ + d) * S_ + s0) = pk;
    }

  // ---- Q/K epilogue (swapped): C row = n (quad*4+reg), col = m (l16); fused RoPE ----
#pragma unroll
  for (int w = 0; w < 2; ++w) {
    u16* dst = (w == 0) ? Q : K;
#pragma unroll
    for (int i4 = 0; i4 < 4; ++i4) {
      int m = mbase + wm * 64 + i4 * 16 + l16;
      int n1 = nbase + (wn >> 1) * 64 + (wn & 1) * 16 + quad * 4;
      int b = m >> 11, s = m & 2047;
      int h = n1 >> 6, d1 = n1 & 63;  // d1 in [0,32), multiple of 4
      float4 c4 = *(const float4*)(cos_t + s * 32 + d1);
      float4 s4 = *(const float4*)(sin_t + s * 32 + d1);
      float y1[4], y2[4];
#pragma unroll
      for (int r = 0; r < 4; ++r) {
        float cr = ((const float*)&c4)[r], sr = ((const float*)&s4)[r];
        float x1 = acc[w][i4][0][r], x2 = acc[w][i4][1][r];
        y1[r] = x1 * cr - x2 * sr;
        y2[r] = x2 * cr + x1 * sr;
      }
      size_t base = ((size_t)(b * H_ + h) * S_ + s) * D_;
      uint2 p1, p2;
      p1.x = packbf2(y1[0], y1[1]);
      p1.y = packbf2(y1[2], y1[3]);
      p2.x = packbf2(y2[0], y2[1]);
      p2.y = packbf2(y2[2], y2[3]);
      *(uint2*)(dst + base + d1) = p1;
      *(uint2*)(dst + base + d1 + 32) = p2;
    }
  }
}

// ---------- flash helpers ----------
// fixed-max softmax (exp2 + truncating perm-pack), then IN-REGISTER q<->key
// transpose via permlane swaps (R4 proven, bit-identical P routing).
__device__ __forceinline__ void softmax_pack(const f32x4 (*s)[4], const float4* mv,
                                             bf16x8 (*pp)[2]) {
#pragma unroll
  for (int qb = 0; qb < 2; ++qb) {
    uint32_t a[4][2];
#pragma unroll
    for (int jt = 0; jt < 4; ++jt) {
      float pf[4];
#pragma unroll
      for (int r = 0; r < 4; ++r) {
        float mvr = ((const float*)&mv[jt])[r];
        pf[r] = __builtin_amdgcn_exp2f(fmaf(s[qb][jt][r], SCALE_LOG2, mvr));
      }
      a[jt][0] = permpack(pf[0], pf[1]);
      a[jt][1] = permpack(pf[2], pf[3]);
    }
#pragma unroll
    for (int kh = 0; kh < 2; ++kh) {
      uint32_t tt[4];
#pragma unroll
      for (int i = 0; i < 2; ++i) {
        auto r1 = __builtin_amdgcn_permlane32_swap(a[2 * kh][i], a[2 * kh + 1][i],
                                                   false, false);
        auto r2 = __builtin_amdgcn_permlane16_swap(r1[0], r1[1], false, false);
        tt[i] = r2[0];      // T[kh][0+i]
        tt[2 + i] = r2[1];  // T[kh][2+i]
      }
      union { uint32_t u[4]; bf16x8 v; } cv;
      cv.u[0] = tt[0]; cv.u[1] = tt[1]; cv.u[2] = tt[2]; cv.u[3] = tt[3];
      pp[qb][kh] = cv.v;
    }
  }
}

// ---------------- Flash attention: LDS-FREE register streaming ----------------
// K/V per (b,h) = 256 KB each -> L2-resident; staging them through LDS was the
// bottleneck (4 waves/block read IDENTICAL frags: 64KB LDS reads + 16KB writes per
// block-tile ~= LDS BW ceiling; explains R5's occupancy-null). Now each wave loads
// its 8 K-frags + 8 V-frags per tile DIRECTLY global->reg (per-lane 16B contiguous,
// full 64B-line utilization; co-resident waves hit L1 on shared lines). Frag regs
// are reloaded for tile kt+1 right after last use (QK for kf, PV for vf): wait
// distance ~400-500cy >> L2 latency. No LDS, no barriers -> waves free-run.
// Same-iteration PV (lag-1 existed only for LDS buffer lifetime). grid (16, 32).
__global__ __launch_bounds__(256, 2) void flash_kernel(
    const u16* __restrict__ Q, const u16* __restrict__ K, const u16* __restrict__ Vt,
    const float* __restrict__ mask2, float* __restrict__ out) {
  int tid = threadIdx.x, wave = tid >> 6;
  int lane = tid & 63;
  int quad = lane >> 4, l16 = lane & 15;
  int bh = blockIdx.y, b = bh >> 4, h = bh & 15;
  int qw = blockIdx.x * 128 + wave * 32;
  const float* m2row = mask2 + b * S_;
  // per-lane frag base pointers (verified identical to the old LDS frag mapping):
  // kf[jt][kh] = K[bh][kt*64 + jt*16 + l16][kh*32 + quad*8 .. +8]
  const u16* kptr = K + (size_t)bh * S_ * D_ + (size_t)l16 * D_ + quad * 8;
  // vf[jd][kh] = Vt[bh][jd*16 + l16][kt*64 + kh*32 + quad*8 .. +8]
  const u16* vptr = Vt + (size_t)bh * D_ * S_ + (size_t)l16 * S_ + quad * 8;

  bf16x8 qfrag[2][2];
#pragma unroll
  for (int qb = 0; qb < 2; ++qb) {
    const u16* qp = Q + ((size_t)bh * S_ + qw + qb * 16 + l16) * D_ + quad * 8;
    qfrag[qb][0] = *(const bf16x8*)qp;
    qfrag[qb][1] = *(const bf16x8*)(qp + 32);
  }
  bf16x8 ones;
#pragma unroll
  for (int j = 0; j < 8; ++j) ones[j] = (short)0x3f80;  // bf16 1.0

  f32x4 o[2][4] = {};
  f32x4 lacc[2] = {};

  // prologue: load tile-0 frags + tile-0 mask
  bf16x8 kf[4][2], vf[4][2];
#pragma unroll
  for (int jt = 0; jt < 4; ++jt)
#pragma unroll
    for (int kh = 0; kh < 2; ++kh)
      kf[jt][kh] = *(const bf16x8*)(kptr + (size_t)(jt * 16) * D_ + kh * 32);
#pragma unroll
  for (int jd = 0; jd < 4; ++jd)
#pragma unroll
    for (int kh = 0; kh < 2; ++kh)
      vf[jd][kh] = *(const bf16x8*)(vptr + (size_t)(jd * 16) * S_ + kh * 32);
  float4 mv[4];
#pragma unroll
  for (int jt = 0; jt < 4; ++jt) mv[jt] = *(const float4*)(m2row + jt * 16 + quad * 4);

  for (int kt = 0; kt < 32; ++kt) {
    int ktn = kt + (kt < 31);  // clamped next tile (kt=31 reloads 31: harmless)

    // ---- QK(kt): S^T = K * Q^T, row=key(quad*4+reg), col=q(l16) ----
    f32x4 s[2][4] = {};
    __builtin_amdgcn_s_setprio(1);
#pragma unroll
    for (int jt = 0; jt < 4; ++jt)
#pragma unroll
      for (int kh = 0; kh < 2; ++kh) {
        s[0][jt] = __builtin_amdgcn_mfma_f32_16x16x32_bf16(kf[jt][kh], qfrag[0][kh],
                                                           s[0][jt], 0, 0, 0);
        s[1][jt] = __builtin_amdgcn_mfma_f32_16x16x32_bf16(kf[jt][kh], qfrag[1][kh],
                                                           s[1][jt], 0, 0, 0);
      }
    __builtin_amdgcn_s_setprio(0);

    // prefetch K frags for tile kt+1 (kf regs dead after QK above)
#pragma unroll
    for (int jt = 0; jt < 4; ++jt)
#pragma unroll
      for (int kh = 0; kh < 2; ++kh)
        kf[jt][kh] = *(const bf16x8*)(kptr + ((size_t)ktn * 64 + jt * 16) * D_ + kh * 32);

    // ---- softmax(kt) -> pp (in-register transpose) ----
    bf16x8 pp[2][2];
    softmax_pack(s, mv, pp);
    // mask prefetch for kt+1 (mv dead after softmax)
#pragma unroll
    for (int jt = 0; jt < 4; ++jt)
      mv[jt] = *(const float4*)(m2row + ktn * 64 + jt * 16 + quad * 4);

    // ---- PV(kt), same iteration ----
    __builtin_amdgcn_s_setprio(1);
    lacc[0] = __builtin_amdgcn_mfma_f32_16x16x32_bf16(pp[0][0], ones, lacc[0], 0, 0, 0);
    lacc[0] = __builtin_amdgcn_mfma_f32_16x16x32_bf16(pp[0][1], ones, lacc[0], 0, 0, 0);
    lacc[1] = __builtin_amdgcn_mfma_f32_16x16x32_bf16(pp[1][0], ones, lacc[1], 0, 0, 0);
    lacc[1] = __builtin_amdgcn_mfma_f32_16x16x32_bf16(pp[1][1], ones, lacc[1], 0, 0, 0);
#pragma unroll
    for (int jd = 0; jd < 4; ++jd)
#pragma unroll
      for (int kh = 0; kh < 2; ++kh) {
        o[0][jd] = __builtin_amdgcn_mfma_f32_16x16x32_bf16(pp[0][kh], vf[jd][kh],
                                                           o[0][jd], 0, 0, 0);
        o[1][jd] = __builtin_amdgcn_mfma_f32_16x16x32_bf16(pp[1][kh], vf[jd][kh],
                                                           o[1][jd], 0, 0, 0);
      }
    __builtin_amdgcn_s_setprio(0);

    // prefetch V frags for tile kt+1 (vf regs dead after PV above)
#pragma unroll
    for (int jd = 0; jd < 4; ++jd)
#pragma unroll
      for (int kh = 0; kh < 2; ++kh)
        vf[jd][kh] = *(const bf16x8*)(vptr + (size_t)(jd * 16) * S_ + ktn * 64 + kh * 32);
  }

  // epilogue: lacc[qb][r] holds the full row-sum for q = qw + qb*16 + quad*4 + r
  float inv[2][4];
#pragma unroll
  for (int qb = 0; qb < 2; ++qb)
#pragma unroll
    for (int r = 0; r < 4; ++r) inv[qb][r] = 1.0f / lacc[qb][r];
#pragma unroll
  for (int qb = 0; qb < 2; ++qb)
#pragma unroll
    for (int jd = 0; jd < 4; ++jd) {
#pragma unroll
      for (int r = 0; r < 4; ++r) {
        int d = jd * 16 + l16;
        int q = qw + qb * 16 + quad * 4 + r;
        out[(((size_t)b * S_ + q) * H_ + h) * D_ + d] = o[qb][jd][r] * inv[qb][r];
      }
    }
}

extern "C" void kernel_launch(void* const* d_in, const int* in_sizes, int n_in,
                              void* d_out, int out_size, void* d_ws, size_t ws_size,
                              hipStream_t stream) {
  const float* hid = (const float*)d_in[0];
  const float* mask = (const float*)d_in[1];
  const float* Wq = (const float*)d_in[2];
  const float* Wk = (const float*)d_in[3];
  const float* Wv = (const float*)d_in[4];
  float* out = (float*)d_out;
  char* ws = (char*)d_ws;

  u16* Xbf = (u16*)ws;                              // 8 MB
  u16* Wqb = (u16*)(ws + (8u << 20));               // 2 MB
  u16* Wkb = (u16*)(ws + (10u << 20));              // 2 MB
  u16* Wvb = (u16*)(ws + (12u << 20));              // 2 MB
  u16* Qb = (u16*)(ws + (14u << 20));               // 8 MB (BH,S,D)
  u16* Kb = (u16*)(ws + (22u << 20));               // 8 MB (BH,S,D)
  u16* Vtb = (u16*)(ws + (30u << 20));              // 8 MB (BH,D,S)
  float* cos_t = (float*)(ws + (38u << 20));        // 256 KB
  float* sin_t = (float*)(ws + (38u << 20) + (256u << 10));
  float* mask2 = (float*)(ws + (38u << 20) + (512u << 10));  // 16 KB

  prep_kernel<<<7440, 256, 0, stream>>>(hid, Wq, Wk, Wv, mask, Xbf, Wqb, Wkb, Wvb,
                                        cos_t, sin_t, mask2);
  qkv_gemm_kernel<<<dim3(8, 32), 512, 0, stream>>>(Xbf, Wqb, Wkb, Wvb, cos_t, sin_t,
                                                   Qb, Kb, Vtb);
  flash_kernel<<<dim3(16, 32), 256, 0, stream>>>(Qb, Kb, Vtb, mask2, out);
}

// Round 8
// 161.084 us; speedup vs baseline: 1.4688x; 1.4688x over previous
//
#include <hip/hip_runtime.h>
#include <stdint.h>

typedef unsigned short u16;
typedef short bf16x8 __attribute__((ext_vector_type(8)));
typedef float f32x4 __attribute__((ext_vector_type(4)));

#define S_ 2048
#define HID_ 1024
#define H_ 16
#define D_ 64

#define LOG2E 1.4426950408889634f
#define SCALE_LOG2 0.18033688011112042f   /* 0.125 * log2(e) */
#define MAXC_LOG2 11.541560327111707f     /* 8 * log2(e) */

__device__ __forceinline__ u16 f2bf(float f) {
  uint32_t x = __builtin_bit_cast(uint32_t, f);
  uint32_t r = (x + 0x7fffu + ((x >> 16) & 1u)) >> 16;
  return (u16)r;
}
__device__ __forceinline__ uint32_t packbf2(float a, float b) {
  return (uint32_t)f2bf(a) | ((uint32_t)f2bf(b) << 16);
}
// truncating pack: low16 = bf16(a), high16 = bf16(b), one v_perm_b32
__device__ __forceinline__ uint32_t permpack(float a, float b) {
  return __builtin_amdgcn_perm(__builtin_bit_cast(uint32_t, b),
                               __builtin_bit_cast(uint32_t, a), 0x07060302u);
}

__device__ __forceinline__ void gl2lds16(const void* g, void* l) {
  __builtin_amdgcn_global_load_lds(
      (const __attribute__((address_space(1))) unsigned int*)g,
      (__attribute__((address_space(3))) unsigned int*)l, 16, 0, 0);
}

// ------------- prep: converts + RoPE tables + mask2, one kernel -------------
#define NX_ (1 << 20)
#define NW_ (1 << 18)
#define NROPE_ 65536
__global__ void prep_kernel(const float* __restrict__ X, const float* __restrict__ Wq,
                            const float* __restrict__ Wk, const float* __restrict__ Wv,
                            const float* __restrict__ mask, u16* __restrict__ Xb,
                            u16* __restrict__ Wqb, u16* __restrict__ Wkb,
                            u16* __restrict__ Wvb, float* __restrict__ cos_t,
                            float* __restrict__ sin_t, float* __restrict__ mask2) {
  int i = blockIdx.x * 256 + threadIdx.x;
  if (i < NX_ + 3 * NW_) {
    const float* src;
    u16* dst;
    int off;
    if (i < NX_) {
      src = X; dst = Xb; off = i;
    } else if (i < NX_ + NW_) {
      src = Wq; dst = Wqb; off = i - NX_;
    } else if (i < NX_ + 2 * NW_) {
      src = Wk; dst = Wkb; off = i - NX_ - NW_;
    } else {
      src = Wv; dst = Wvb; off = i - NX_ - 2 * NW_;
    }
    float4 v = ((const float4*)src)[off];
    uint2 packed;
    packed.x = packbf2(v.x, v.y);
    packed.y = packbf2(v.z, v.w);
    ((uint2*)dst)[off] = packed;
  } else if (i < NX_ + 3 * NW_ + NROPE_) {
    int t = i - (NX_ + 3 * NW_);  // 65536 = 2048*32
    int s = t >> 5, j = t & 31;
    float invf = powf(10000.0f, -(float)j * (1.0f / 32.0f));
    float ang = (float)s * invf;
    cos_t[t] = cosf(ang);
    sin_t[t] = sinf(ang);
  } else {
    int t = i - (NX_ + 3 * NW_ + NROPE_);  // 4096 = 2*2048
    mask2[t] = fmaf(mask[t], LOG2E, -MAXC_LOG2);
  }
}

// ---------------- Fused QKV GEMM + counted-vmcnt barriers ----------------
// grid (8, 32) = 256 blocks = 1/CU, zero dispatch tail. 512 threads (8 waves 2m x 4n).
// A staged ONCE per K-step, shared by all 3 B matrices. LDS 128 KB dbuf.
// T4 counted-vmcnt (replaces __syncthreads' full vmcnt(0) drain, which idles the
// whole CU at 1 block/CU):
//   barrier_A                 -> all waves done compute(kk-1): dbuf overwrite safe
//   stage(kk+1) [8 gl2lds]    -> 16 outstanding
//   s_waitcnt vmcnt(8)        -> own tile-kk loads retired (newest 8 still in flight)
//   barrier_B                 -> ALL waves' tile-kk loads retired -> compute(kk)
// The 8 new loads land during compute(kk) instead of stalling at a drain.
__global__ __launch_bounds__(512, 2) void qkv_gemm_kernel(
    const u16* __restrict__ X, const u16* __restrict__ Wq, const u16* __restrict__ Wk,
    const u16* __restrict__ Wv, const float* __restrict__ cos_t,
    const float* __restrict__ sin_t, u16* __restrict__ Q, u16* __restrict__ K,
    u16* __restrict__ Vt) {
  __shared__ char smem[131072];
  int tid = threadIdx.x;
  int lane = tid & 63, wave = tid >> 6;
  int wm = wave >> 2, wn = wave & 3;
  int quad = lane >> 4, l16 = lane & 15;
  int nbase = blockIdx.x * 128;
  int mbase = blockIdx.y * 128;

#define STAGE_ALL(k0, buf)                                                        \
  {                                                                               \
    _Pragma("unroll") for (int it = 0; it < 8; ++it) {                            \
      int j = (it & 1) * 512 + tid;                                               \
      int r = j >> 3, gs = j & 7, gsrc = gs ^ (r & 7);                            \
      const u16* src; int rb;                                                     \
      if ((it >> 1) == 0)      { src = X;  rb = mbase + r; }                      \
      else if ((it >> 1) == 1) { src = Wq; rb = nbase + r; }                      \
      else if ((it >> 1) == 2) { src = Wk; rb = nbase + r; }                      \
      else                     { src = Wv; rb = nbase + r; }                      \
      gl2lds16(src + (size_t)rb * HID_ + (k0) + gsrc * 8,                         \
               (buf) + (it >> 1) * 16384 + j * 16);                               \
    }                                                                             \
  }

  STAGE_ALL(0, smem)  // tile 0 -> buf 0 (8 loads outstanding)

  f32x4 acc[3][4][2] = {};  // [which][i4 m-block][j2 n-pair]

  for (int kk = 0; kk < 16; ++kk) {
    const char* buf = smem + (kk & 1) * 65536;

    if (kk > 0) __builtin_amdgcn_s_barrier();  // A: all waves done compute(kk-1)

    if (kk < 15) {
      STAGE_ALL((kk + 1) * 64, smem + ((kk + 1) & 1) * 65536)  // +8 -> 16 outstanding
      asm volatile("s_waitcnt vmcnt(8)" ::: "memory");  // tile kk retired (own)
    } else {
      asm volatile("s_waitcnt vmcnt(0)" ::: "memory");  // tail: drain tile 15
    }
    __builtin_amdgcn_s_barrier();  // B: tile kk staged by ALL waves
    __builtin_amdgcn_sched_barrier(0);  // pin LDS reads below barrier_B

#pragma unroll
    for (int kh = 0; kh < 2; ++kh) {
      bf16x8 afrag[4];
#pragma unroll
      for (int i4 = 0; i4 < 4; ++i4) {
        int r = wm * 64 + i4 * 16 + l16;
        int L = r * 8 + ((kh * 4 + quad) ^ (r & 7));
        afrag[i4] = *(const bf16x8*)(buf + L * 16);
      }
#pragma unroll
      for (int w = 0; w < 3; ++w) {
        const char* Bs = buf + 16384 + w * 16384;
        bf16x8 bfrag[2];
#pragma unroll
        for (int j2 = 0; j2 < 2; ++j2) {
          int r = (wn >> 1) * 64 + (wn & 1) * 16 + j2 * 32 + l16;
          int L = r * 8 + ((kh * 4 + quad) ^ (r & 7));
          bfrag[j2] = *(const bf16x8*)(Bs + L * 16);
        }
        if (w == 2) {
#pragma unroll
          for (int i4 = 0; i4 < 4; ++i4)
#pragma unroll
            for (int j2 = 0; j2 < 2; ++j2)
              acc[2][i4][j2] = __builtin_amdgcn_mfma_f32_16x16x32_bf16(
                  afrag[i4], bfrag[j2], acc[2][i4][j2], 0, 0, 0);
        } else if (w == 1) {
#pragma unroll
          for (int i4 = 0; i4 < 4; ++i4)
#pragma unroll
            for (int j2 = 0; j2 < 2; ++j2)
              acc[1][i4][j2] = __builtin_amdgcn_mfma_f32_16x16x32_bf16(
                  bfrag[j2], afrag[i4], acc[1][i4][j2], 0, 0, 0);
        } else {
#pragma unroll
          for (int i4 = 0; i4 < 4; ++i4)
#pragma unroll
            for (int j2 = 0; j2 < 2; ++j2)
              acc[0][i4][j2] = __builtin_amdgcn_mfma_f32_16x16x32_bf16(
                  bfrag[j2], afrag[i4], acc[0][i4][j2], 0, 0, 0);
        }
      }
    }
  }
#undef STAGE_ALL

  // ---- V epilogue (w=2, non-swapped): C row = m (quad*4+reg), col = n (l16) ----
#pragma unroll
  for (int i4 = 0; i4 < 4; ++i4)
#pragma unroll
    for (int j2 = 0; j2 < 2; ++j2) {
      int m = mbase + wm * 64 + i4 * 16 + quad * 4;
      int n = nbase + (wn >> 1) * 64 + (wn & 1) * 16 + j2 * 32 + l16;
      int b = m >> 11, s0 = m & 2047;
      int h = n >> 6, d = n & 63;
      uint2 pk;
      pk.x = packbf2(acc[2][i4][j2][0], acc[2][i4][j2][1]);
      pk.y = packbf2(acc[2][i4][j2][2], acc[2][i4][j2][3]);
      *(uint2*)(Vt + (((size_t)(b * H_ + h)) * D_ + d) * S_ + s0) = pk;
    }

  // ---- Q/K epilogue (swapped): C row = n (quad*4+reg), col = m (l16); fused RoPE ----
#pragma unroll
  for (int w = 0; w < 2; ++w) {
    u16* dst = (w == 0) ? Q : K;
#pragma unroll
    for (int i4 = 0; i4 < 4; ++i4) {
      int m = mbase + wm * 64 + i4 * 16 + l16;
      int n1 = nbase + (wn >> 1) * 64 + (wn & 1) * 16 + quad * 4;
      int b = m >> 11, s = m & 2047;
      int h = n1 >> 6, d1 = n1 & 63;  // d1 in [0,32), multiple of 4
      float4 c4 = *(const float4*)(cos_t + s * 32 + d1);
      float4 s4 = *(const float4*)(sin_t + s * 32 + d1);
      float y1[4], y2[4];
#pragma unroll
      for (int r = 0; r < 4; ++r) {
        float cr = ((const float*)&c4)[r], sr = ((const float*)&s4)[r];
        float x1 = acc[w][i4][0][r], x2 = acc[w][i4][1][r];
        y1[r] = x1 * cr - x2 * sr;
        y2[r] = x2 * cr + x1 * sr;
      }
      size_t base = ((size_t)(b * H_ + h) * S_ + s) * D_;
      uint2 p1, p2;
      p1.x = packbf2(y1[0], y1[1]);
      p1.y = packbf2(y1[2], y1[3]);
      p2.x = packbf2(y2[0], y2[1]);
      p2.y = packbf2(y2[2], y2[3]);
      *(uint2*)(dst + base + d1) = p1;
      *(uint2*)(dst + base + d1 + 32) = p2;
    }
  }
}

// ---------- flash helpers (R4/R6 proven) ----------
// PV step: P fragments come from REGISTERS (pp), V frags from LDS (read once,
// reused across both q-blocks).
__device__ __forceinline__ void pv_step(const bf16x8 (*pp)[2], const char* Vp, int quad,
                                        int l16, const bf16x8& ones, f32x4 (*o)[4],
                                        f32x4* lacc) {
  lacc[0] = __builtin_amdgcn_mfma_f32_16x16x32_bf16(pp[0][0], ones, lacc[0], 0, 0, 0);
  lacc[0] = __builtin_amdgcn_mfma_f32_16x16x32_bf16(pp[0][1], ones, lacc[0], 0, 0, 0);
  lacc[1] = __builtin_amdgcn_mfma_f32_16x16x32_bf16(pp[1][0], ones, lacc[1], 0, 0, 0);
  lacc[1] = __builtin_amdgcn_mfma_f32_16x16x32_bf16(pp[1][1], ones, lacc[1], 0, 0, 0);
#pragma unroll
  for (int jd = 0; jd < 4; ++jd) {
    int r = jd * 16 + l16;
#pragma unroll
    for (int kh = 0; kh < 2; ++kh) {
      int L = r * 8 + ((kh * 4 + quad) ^ (r & 7));
      bf16x8 vf = *(const bf16x8*)(Vp + L * 16);
      o[0][jd] = __builtin_amdgcn_mfma_f32_16x16x32_bf16(pp[0][kh], vf, o[0][jd], 0, 0, 0);
      o[1][jd] = __builtin_amdgcn_mfma_f32_16x16x32_bf16(pp[1][kh], vf, o[1][jd], 0, 0, 0);
    }
  }
}

// S^T = K * Q^T : row=key (quad*4+reg), col=q (l16). kf read once, 2 q-blocks.
__device__ __forceinline__ void qk_step(const char* Ks, const bf16x8 (*qfrag)[2], int quad,
                                        int l16, f32x4 (*s)[4]) {
#pragma unroll
  for (int jt = 0; jt < 4; ++jt) {
    int r = jt * 16 + l16;
#pragma unroll
    for (int kh = 0; kh < 2; ++kh) {
      int L = r * 8 + ((kh * 4 + quad) ^ (r & 7));
      bf16x8 kf = *(const bf16x8*)(Ks + L * 16);
      s[0][jt] = __builtin_amdgcn_mfma_f32_16x16x32_bf16(kf, qfrag[0][kh], s[0][jt], 0, 0, 0);
      s[1][jt] = __builtin_amdgcn_mfma_f32_16x16x32_bf16(kf, qfrag[1][kh], s[1][jt], 0, 0, 0);
    }
  }
}

// fixed-max softmax (exp2 + truncating perm-pack), then IN-REGISTER q<->key
// transpose via permlane swaps (replaces the P LDS round-trip).
__device__ __forceinline__ void softmax_pack(const f32x4 (*s)[4], const float4* mv,
                                             bf16x8 (*pp)[2]) {
#pragma unroll
  for (int qb = 0; qb < 2; ++qb) {
    uint32_t a[4][2];
#pragma unroll
    for (int jt = 0; jt < 4; ++jt) {
      float pf[4];
#pragma unroll
      for (int r = 0; r < 4; ++r) {
        float mvr = ((const float*)&mv[jt])[r];
        pf[r] = __builtin_amdgcn_exp2f(fmaf(s[qb][jt][r], SCALE_LOG2, mvr));
      }
      a[jt][0] = permpack(pf[0], pf[1]);
      a[jt][1] = permpack(pf[2], pf[3]);
    }
#pragma unroll
    for (int kh = 0; kh < 2; ++kh) {
      uint32_t tt[4];
#pragma unroll
      for (int i = 0; i < 2; ++i) {
        auto r1 = __builtin_amdgcn_permlane32_swap(a[2 * kh][i], a[2 * kh + 1][i],
                                                   false, false);
        auto r2 = __builtin_amdgcn_permlane16_swap(r1[0], r1[1], false, false);
        tt[i] = r2[0];      // T[kh][0+i]
        tt[2 + i] = r2[1];  // T[kh][2+i]
      }
      union { uint32_t u[4]; bf16x8 v; } cv;
      cv.u[0] = tt[0]; cv.u[1] = tt[1]; cv.u[2] = tt[2]; cv.u[3] = tt[3];
      pp[qb][kh] = cv.v;
    }
  }
}

__device__ __forceinline__ void stage_kv(const u16* Kbase, const u16* Vbase, char* Kn,
                                         int nb, int tid) {
#pragma unroll
  for (int half = 0; half < 2; ++half) {
    int i = half * 256 + tid;
    int r = i >> 3, gs = i & 7, gsrc = gs ^ (r & 7);
    gl2lds16(Kbase + (size_t)(nb + r) * D_ + gsrc * 8, Kn + i * 16);
    gl2lds16(Vbase + (size_t)r * S_ + nb + gsrc * 8, Kn + 8192 + i * 16);
  }
}

// ---------------- Flash attention (R6 proven, reverted): 256 threads, 4 waves x 32 q ----------------
// grid (16, 32), 2 blocks/CU. 64-key tiles, triple-buffered K/V (48 KB LDS),
// P entirely in registers (permlane transpose), 1 barrier/tile.
// Steady iter kt: stage kt+1; PV(kt-1) from pp regs; QK(kt); softmax+permlane -> pp.
__global__ __launch_bounds__(256, 2) void flash_kernel(
    const u16* __restrict__ Q, const u16* __restrict__ K, const u16* __restrict__ Vt,
    const float* __restrict__ mask2, float* __restrict__ out) {
  __shared__ char smem[49152];  // K/V: 3 bufs @ b*16384 (K@+0, V@+8192)
  int tid = threadIdx.x, wave = tid >> 6;
  int lane = tid & 63;
  int quad = lane >> 4, l16 = lane & 15;
  int bh = blockIdx.y, b = bh >> 4, h = bh & 15;
  int qbase = blockIdx.x * 128;
  int qw = qbase + wave * 32;
  const float* m2row = mask2 + b * S_;
  const u16* Kbase = K + (size_t)bh * S_ * D_;
  const u16* Vbase = Vt + (size_t)bh * D_ * S_;

  bf16x8 qfrag[2][2];
#pragma unroll
  for (int qb = 0; qb < 2; ++qb) {
    const u16* qp = Q + ((size_t)bh * S_ + qw + qb * 16 + l16) * D_ + quad * 8;
    qfrag[qb][0] = *(const bf16x8*)qp;
    qfrag[qb][1] = *(const bf16x8*)(qp + 32);
  }
  bf16x8 ones;
#pragma unroll
  for (int j = 0; j < 8; ++j) ones[j] = (short)0x3f80;  // bf16 1.0

  f32x4 o[2][4] = {};
  f32x4 lacc[2] = {};
  bf16x8 pp[2][2];  // P(kt) fragments, consumed by PV in iter kt+1

  // stage tile 0 into buffer 0
  stage_kv(Kbase, Vbase, smem, 0, tid);
  // mask prefetch for kt=0 (per-key, indexed by jt*16 + quad*4 + r)
  float4 mv[4];
#pragma unroll
  for (int jt = 0; jt < 4; ++jt) mv[jt] = *(const float4*)(m2row + jt * 16 + quad * 4);

  // ---- kt = 0 (peeled: no PV) ----
  {
    __syncthreads();  // tile 0 staged
    stage_kv(Kbase, Vbase, smem + 16384, 64, tid);  // tile 1 -> buf 1
    f32x4 s[2][4] = {};
    __builtin_amdgcn_s_setprio(1);
    qk_step(smem, qfrag, quad, l16, s);
    __builtin_amdgcn_s_setprio(0);
    softmax_pack(s, mv, pp);
#pragma unroll
    for (int jt = 0; jt < 4; ++jt)
      mv[jt] = *(const float4*)(m2row + 64 + jt * 16 + quad * 4);
  }

  // ---- steady state kt = 1..30 ----
  for (int kt = 1; kt <= 30; ++kt) {
    char* Ks = smem + (kt % 3) * 16384;
    __syncthreads();  // staging of tile kt complete; buf (kt+1)%3 free (PV(kt-2) done)
    stage_kv(Kbase, Vbase, smem + ((kt + 1) % 3) * 16384, (kt + 1) * 64, tid);

    __builtin_amdgcn_s_setprio(1);
    // PV for tile kt-1 from pp regs + V in buf (kt-1)%3
    const char* Vp = smem + ((kt - 1) % 3) * 16384 + 8192;
    pv_step(pp, Vp, quad, l16, ones, o, lacc);

    f32x4 s[2][4] = {};
    qk_step(Ks, qfrag, quad, l16, s);
    __builtin_amdgcn_s_setprio(0);

    softmax_pack(s, mv, pp);  // overwrites pp with P(kt) (PV above already consumed it)
#pragma unroll
    for (int jt = 0; jt < 4; ++jt)
      mv[jt] = *(const float4*)(m2row + (kt + 1) * 64 + jt * 16 + quad * 4);
  }

  // ---- kt = 31 (peeled: no stage, no mask prefetch) ----
  {
    __syncthreads();
    __builtin_amdgcn_s_setprio(1);
    pv_step(pp, smem + 0 * 16384 + 8192, quad, l16, ones, o, lacc);  // PV(30), buf 0
    f32x4 s[2][4] = {};
    qk_step(smem + 16384, qfrag, quad, l16, s);  // tile 31 in buf 1
    __builtin_amdgcn_s_setprio(0);
    softmax_pack(s, mv, pp);
  }

  // drain: PV for tile 31 (V in buf 31%3 = 1)
  pv_step(pp, smem + 16384 + 8192, quad, l16, ones, o, lacc);

  // epilogue: lacc[qb][r] holds the full row-sum for q = qw + qb*16 + quad*4 + r
  float inv[2][4];
#pragma unroll
  for (int qb = 0; qb < 2; ++qb)
#pragma unroll
    for (int r = 0; r < 4; ++r) inv[qb][r] = 1.0f / lacc[qb][r];
#pragma unroll
  for (int qb = 0; qb < 2; ++qb)
#pragma unroll
    for (int jd = 0; jd < 4; ++jd) {
#pragma unroll
      for (int r = 0; r < 4; ++r) {
        int d = jd * 16 + l16;
        int q = qw + qb * 16 + quad * 4 + r;
        out[(((size_t)b * S_ + q) * H_ + h) * D_ + d] = o[qb][jd][r] * inv[qb][r];
      }
    }
}

extern "C" void kernel_launch(void* const* d_in, const int* in_sizes, int n_in,
                              void* d_out, int out_size, void* d_ws, size_t ws_size,
                              hipStream_t stream) {
  const float* hid = (const float*)d_in[0];
  const float* mask = (const float*)d_in[1];
  const float* Wq = (const float*)d_in[2];
  const float* Wk = (const float*)d_in[3];
  const float* Wv = (const float*)d_in[4];
  float* out = (float*)d_out;
  char* ws = (char*)d_ws;

  u16* Xbf = (u16*)ws;                              // 8 MB
  u16* Wqb = (u16*)(ws + (8u << 20));               // 2 MB
  u16* Wkb = (u16*)(ws + (10u << 20));              // 2 MB
  u16* Wvb = (u16*)(ws + (12u << 20));              // 2 MB
  u16* Qb = (u16*)(ws + (14u << 20));               // 8 MB (BH,S,D)
  u16* Kb = (u16*)(ws + (22u << 20));               // 8 MB (BH,S,D)
  u16* Vtb = (u16*)(ws + (30u << 20));              // 8 MB (BH,D,S)
  float* cos_t = (float*)(ws + (38u << 20));        // 256 KB
  float* sin_t = (float*)(ws + (38u << 20) + (256u << 10));
  float* mask2 = (float*)(ws + (38u << 20) + (512u << 10));  // 16 KB

  prep_kernel<<<7440, 256, 0, stream>>>(hid, Wq, Wk, Wv, mask, Xbf, Wqb, Wkb, Wvb,
                                        cos_t, sin_t, mask2);
  qkv_gemm_kernel<<<dim3(8, 32), 512, 0, stream>>>(Xbf, Wqb, Wkb, Wvb, cos_t, sin_t,
                                                   Qb, Kb, Vtb);
  flash_kernel<<<dim3(16, 32), 256, 0, stream>>>(Qb, Kb, Vtb, mask2, out);
}

// Round 9
// 159.211 us; speedup vs baseline: 1.4861x; 1.0118x over previous
//
#include <hip/hip_runtime.h>
#include <stdint.h>

typedef unsigned short u16;
typedef short bf16x8 __attribute__((ext_vector_type(8)));
typedef float f32x4 __attribute__((ext_vector_type(4)));

#define S_ 2048
#define HID_ 1024
#define H_ 16
#define D_ 64

#define LOG2E 1.4426950408889634f
#define SCALE_LOG2 0.18033688011112042f   /* 0.125 * log2(e) */
#define MAXC_LOG2 11.541560327111707f     /* 8 * log2(e) */

__device__ __forceinline__ u16 f2bf(float f) {
  uint32_t x = __builtin_bit_cast(uint32_t, f);
  uint32_t r = (x + 0x7fffu + ((x >> 16) & 1u)) >> 16;
  return (u16)r;
}
__device__ __forceinline__ uint32_t packbf2(float a, float b) {
  return (uint32_t)f2bf(a) | ((uint32_t)f2bf(b) << 16);
}
// truncating pack: low16 = bf16(a), high16 = bf16(b), one v_perm_b32
__device__ __forceinline__ uint32_t permpack(float a, float b) {
  return __builtin_amdgcn_perm(__builtin_bit_cast(uint32_t, b),
                               __builtin_bit_cast(uint32_t, a), 0x07060302u);
}

__device__ __forceinline__ void gl2lds16(const void* g, void* l) {
  __builtin_amdgcn_global_load_lds(
      (const __attribute__((address_space(1))) unsigned int*)g,
      (__attribute__((address_space(3))) unsigned int*)l, 16, 0, 0);
}

// ------------- prep: converts + RoPE tables + mask2, one kernel -------------
#define NX_ (1 << 20)
#define NW_ (1 << 18)
#define NROPE_ 65536
__global__ void prep_kernel(const float* __restrict__ X, const float* __restrict__ Wq,
                            const float* __restrict__ Wk, const float* __restrict__ Wv,
                            const float* __restrict__ mask, u16* __restrict__ Xb,
                            u16* __restrict__ Wqb, u16* __restrict__ Wkb,
                            u16* __restrict__ Wvb, float* __restrict__ cos_t,
                            float* __restrict__ sin_t, float* __restrict__ mask2) {
  int i = blockIdx.x * 256 + threadIdx.x;
  if (i < NX_ + 3 * NW_) {
    const float* src;
    u16* dst;
    int off;
    if (i < NX_) {
      src = X; dst = Xb; off = i;
    } else if (i < NX_ + NW_) {
      src = Wq; dst = Wqb; off = i - NX_;
    } else if (i < NX_ + 2 * NW_) {
      src = Wk; dst = Wkb; off = i - NX_ - NW_;
    } else {
      src = Wv; dst = Wvb; off = i - NX_ - 2 * NW_;
    }
    float4 v = ((const float4*)src)[off];
    uint2 packed;
    packed.x = packbf2(v.x, v.y);
    packed.y = packbf2(v.z, v.w);
    ((uint2*)dst)[off] = packed;
  } else if (i < NX_ + 3 * NW_ + NROPE_) {
    int t = i - (NX_ + 3 * NW_);  // 65536 = 2048*32
    int s = t >> 5, j = t & 31;
    float invf = powf(10000.0f, -(float)j * (1.0f / 32.0f));
    float ang = (float)s * invf;
    cos_t[t] = cosf(ang);
    sin_t[t] = sinf(ang);
  } else {
    int t = i - (NX_ + 3 * NW_ + NROPE_);  // 4096 = 2*2048
    mask2[t] = fmaf(mask[t], LOG2E, -MAXC_LOG2);
  }
}

// ---------------- Fused QKV GEMM (R6 proven, reverted): one block, Q+K+V ----------------
// grid (8, 32) = 256 blocks = 1/CU, zero dispatch tail. 512 threads (8 waves 2m x 4n).
// A staged ONCE per K-step, shared by all 3 B matrices. LDS 128 KB dbuf,
// stage-before-compute, 1 barrier/K-step.
__global__ __launch_bounds__(512, 2) void qkv_gemm_kernel(
    const u16* __restrict__ X, const u16* __restrict__ Wq, const u16* __restrict__ Wk,
    const u16* __restrict__ Wv, const float* __restrict__ cos_t,
    const float* __restrict__ sin_t, u16* __restrict__ Q, u16* __restrict__ K,
    u16* __restrict__ Vt) {
  __shared__ char smem[131072];
  int tid = threadIdx.x;
  int lane = tid & 63, wave = tid >> 6;
  int wm = wave >> 2, wn = wave & 3;
  int quad = lane >> 4, l16 = lane & 15;
  int nbase = blockIdx.x * 128;
  int mbase = blockIdx.y * 128;

#define STAGE_ALL(k0, buf)                                                        \
  {                                                                               \
    _Pragma("unroll") for (int it = 0; it < 8; ++it) {                            \
      int j = (it & 1) * 512 + tid;                                               \
      int r = j >> 3, gs = j & 7, gsrc = gs ^ (r & 7);                            \
      const u16* src; int rb;                                                     \
      if ((it >> 1) == 0)      { src = X;  rb = mbase + r; }                      \
      else if ((it >> 1) == 1) { src = Wq; rb = nbase + r; }                      \
      else if ((it >> 1) == 2) { src = Wk; rb = nbase + r; }                      \
      else                     { src = Wv; rb = nbase + r; }                      \
      gl2lds16(src + (size_t)rb * HID_ + (k0) + gsrc * 8,                         \
               (buf) + (it >> 1) * 16384 + j * 16);                               \
    }                                                                             \
  }

  STAGE_ALL(0, smem)  // tile 0 -> buf 0

  f32x4 acc[3][4][2] = {};  // [which][i4 m-block][j2 n-pair]

  for (int kk = 0; kk < 16; ++kk) {
    const char* buf = smem + (kk & 1) * 65536;
    __syncthreads();  // staging of tile kk complete

    if (kk < 15)  // stage tile kk+1 into other buffer (its reads finished pre-barrier)
      STAGE_ALL((kk + 1) * 64, smem + ((kk + 1) & 1) * 65536)

#pragma unroll
    for (int kh = 0; kh < 2; ++kh) {
      bf16x8 afrag[4];
#pragma unroll
      for (int i4 = 0; i4 < 4; ++i4) {
        int r = wm * 64 + i4 * 16 + l16;
        int L = r * 8 + ((kh * 4 + quad) ^ (r & 7));
        afrag[i4] = *(const bf16x8*)(buf + L * 16);
      }
#pragma unroll
      for (int w = 0; w < 3; ++w) {
        const char* Bs = buf + 16384 + w * 16384;
        bf16x8 bfrag[2];
#pragma unroll
        for (int j2 = 0; j2 < 2; ++j2) {
          int r = (wn >> 1) * 64 + (wn & 1) * 16 + j2 * 32 + l16;
          int L = r * 8 + ((kh * 4 + quad) ^ (r & 7));
          bfrag[j2] = *(const bf16x8*)(Bs + L * 16);
        }
        if (w == 2) {
#pragma unroll
          for (int i4 = 0; i4 < 4; ++i4)
#pragma unroll
            for (int j2 = 0; j2 < 2; ++j2)
              acc[2][i4][j2] = __builtin_amdgcn_mfma_f32_16x16x32_bf16(
                  afrag[i4], bfrag[j2], acc[2][i4][j2], 0, 0, 0);
        } else if (w == 1) {
#pragma unroll
          for (int i4 = 0; i4 < 4; ++i4)
#pragma unroll
            for (int j2 = 0; j2 < 2; ++j2)
              acc[1][i4][j2] = __builtin_amdgcn_mfma_f32_16x16x32_bf16(
                  bfrag[j2], afrag[i4], acc[1][i4][j2], 0, 0, 0);
        } else {
#pragma unroll
          for (int i4 = 0; i4 < 4; ++i4)
#pragma unroll
            for (int j2 = 0; j2 < 2; ++j2)
              acc[0][i4][j2] = __builtin_amdgcn_mfma_f32_16x16x32_bf16(
                  bfrag[j2], afrag[i4], acc[0][i4][j2], 0, 0, 0);
        }
      }
    }
  }
#undef STAGE_ALL

  // ---- V epilogue (w=2, non-swapped): C row = m (quad*4+reg), col = n (l16) ----
#pragma unroll
  for (int i4 = 0; i4 < 4; ++i4)
#pragma unroll
    for (int j2 = 0; j2 < 2; ++j2) {
      int m = mbase + wm * 64 + i4 * 16 + quad * 4;
      int n = nbase + (wn >> 1) * 64 + (wn & 1) * 16 + j2 * 32 + l16;
      int b = m >> 11, s0 = m & 2047;
      int h = n >> 6, d = n & 63;
      uint2 pk;
      pk.x = packbf2(acc[2][i4][j2][0], acc[2][i4][j2][1]);
      pk.y = packbf2(acc[2][i4][j2][2], acc[2][i4][j2][3]);
      *(uint2*)(Vt + (((size_t)(b * H_ + h)) * D_ + d) * S_ + s0) = pk;
    }

  // ---- Q/K epilogue (swapped): C row = n (quad*4+reg), col = m (l16); fused RoPE ----
#pragma unroll
  for (int w = 0; w < 2; ++w) {
    u16* dst = (w == 0) ? Q : K;
#pragma unroll
    for (int i4 = 0; i4 < 4; ++i4) {
      int m = mbase + wm * 64 + i4 * 16 + l16;
      int n1 = nbase + (wn >> 1) * 64 + (wn & 1) * 16 + quad * 4;
      int b = m >> 11, s = m & 2047;
      int h = n1 >> 6, d1 = n1 & 63;  // d1 in [0,32), multiple of 4
      float4 c4 = *(const float4*)(cos_t + s * 32 + d1);
      float4 s4 = *(const float4*)(sin_t + s * 32 + d1);
      float y1[4], y2[4];
#pragma unroll
      for (int r = 0; r < 4; ++r) {
        float cr = ((const float*)&c4)[r], sr = ((const float*)&s4)[r];
        float x1 = acc[w][i4][0][r], x2 = acc[w][i4][1][r];
        y1[r] = x1 * cr - x2 * sr;
        y2[r] = x2 * cr + x1 * sr;
      }
      size_t base = ((size_t)(b * H_ + h) * S_ + s) * D_;
      uint2 p1, p2;
      p1.x = packbf2(y1[0], y1[1]);
      p1.y = packbf2(y1[2], y1[3]);
      p2.x = packbf2(y2[0], y2[1]);
      p2.y = packbf2(y2[2], y2[3]);
      *(uint2*)(dst + base + d1) = p1;
      *(uint2*)(dst + base + d1 + 32) = p2;
    }
  }
}

// ---------- flash helpers (R4/R6 proven primitives) ----------
// PV step: P fragments from REGISTERS (pp), V frags from LDS (read once, 2 q-blocks).
__device__ __forceinline__ void pv_step(const bf16x8 (*pp)[2], const char* Vp, int quad,
                                        int l16, const bf16x8& ones, f32x4 (*o)[4],
                                        f32x4* lacc) {
  lacc[0] = __builtin_amdgcn_mfma_f32_16x16x32_bf16(pp[0][0], ones, lacc[0], 0, 0, 0);
  lacc[0] = __builtin_amdgcn_mfma_f32_16x16x32_bf16(pp[0][1], ones, lacc[0], 0, 0, 0);
  lacc[1] = __builtin_amdgcn_mfma_f32_16x16x32_bf16(pp[1][0], ones, lacc[1], 0, 0, 0);
  lacc[1] = __builtin_amdgcn_mfma_f32_16x16x32_bf16(pp[1][1], ones, lacc[1], 0, 0, 0);
#pragma unroll
  for (int jd = 0; jd < 4; ++jd) {
    int r = jd * 16 + l16;
#pragma unroll
    for (int kh = 0; kh < 2; ++kh) {
      int L = r * 8 + ((kh * 4 + quad) ^ (r & 7));
      bf16x8 vf = *(const bf16x8*)(Vp + L * 16);
      o[0][jd] = __builtin_amdgcn_mfma_f32_16x16x32_bf16(pp[0][kh], vf, o[0][jd], 0, 0, 0);
      o[1][jd] = __builtin_amdgcn_mfma_f32_16x16x32_bf16(pp[1][kh], vf, o[1][jd], 0, 0, 0);
    }
  }
}

// S^T = K * Q^T : row=key (quad*4+reg), col=q (l16). kf read once, 2 q-blocks.
// Accumulates into s (caller zeroes).
__device__ __forceinline__ void qk_step(const char* Ks, const bf16x8 (*qfrag)[2], int quad,
                                        int l16, f32x4 (*s)[4]) {
#pragma unroll
  for (int jt = 0; jt < 4; ++jt) {
    int r = jt * 16 + l16;
#pragma unroll
    for (int kh = 0; kh < 2; ++kh) {
      int L = r * 8 + ((kh * 4 + quad) ^ (r & 7));
      bf16x8 kf = *(const bf16x8*)(Ks + L * 16);
      s[0][jt] = __builtin_amdgcn_mfma_f32_16x16x32_bf16(kf, qfrag[0][kh], s[0][jt], 0, 0, 0);
      s[1][jt] = __builtin_amdgcn_mfma_f32_16x16x32_bf16(kf, qfrag[1][kh], s[1][jt], 0, 0, 0);
    }
  }
}

// fixed-max softmax (exp2 + truncating perm-pack), then IN-REGISTER q<->key
// transpose via permlane swaps.
__device__ __forceinline__ void softmax_pack(const f32x4 (*s)[4], const float4* mv,
                                             bf16x8 (*pp)[2]) {
#pragma unroll
  for (int qb = 0; qb < 2; ++qb) {
    uint32_t a[4][2];
#pragma unroll
    for (int jt = 0; jt < 4; ++jt) {
      float pf[4];
#pragma unroll
      for (int r = 0; r < 4; ++r) {
        float mvr = ((const float*)&mv[jt])[r];
        pf[r] = __builtin_amdgcn_exp2f(fmaf(s[qb][jt][r], SCALE_LOG2, mvr));
      }
      a[jt][0] = permpack(pf[0], pf[1]);
      a[jt][1] = permpack(pf[2], pf[3]);
    }
#pragma unroll
    for (int kh = 0; kh < 2; ++kh) {
      uint32_t tt[4];
#pragma unroll
      for (int i = 0; i < 2; ++i) {
        auto r1 = __builtin_amdgcn_permlane32_swap(a[2 * kh][i], a[2 * kh + 1][i],
                                                   false, false);
        auto r2 = __builtin_amdgcn_permlane16_swap(r1[0], r1[1], false, false);
        tt[i] = r2[0];      // T[kh][0+i]
        tt[2 + i] = r2[1];  // T[kh][2+i]
      }
      union { uint32_t u[4]; bf16x8 v; } cv;
      cv.u[0] = tt[0]; cv.u[1] = tt[1]; cv.u[2] = tt[2]; cv.u[3] = tt[3];
      pp[qb][kh] = cv.v;
    }
  }
}

// stage one 64-key tile: K -> Kd (64 keys x 64 d), V -> Vd (64 d x 64 keys).
__device__ __forceinline__ void stage_kv2(const u16* Kbase, const u16* Vbase, char* Kd,
                                          char* Vd, int nb, int tid) {
#pragma unroll
  for (int hh = 0; hh < 2; ++hh) {
    int i = hh * 256 + tid;
    int r = i >> 3, gs = i & 7, gsrc = gs ^ (r & 7);
    gl2lds16(Kbase + (size_t)(nb + r) * D_ + gsrc * 8, Kd + i * 16);
    gl2lds16(Vbase + (size_t)r * S_ + nb + gsrc * 8, Vd + i * 16);
  }
}

// ---------------- Flash attention: T15 double-pipeline, 4 waves x 32 q ----------------
// grid (16, 32), 2 blocks/CU. LDS 48 KB: K dbuf (2x8K @0), V quad-buf (4x8K @16K).
// Iter kt body: { stage(kt+1); PV(kt-2) <- pp(kt-2); QK(kt) -> S_cur;
//                 softmax(S_prev = s(kt-1)) -> pp(kt-1); mv <- mask(kt) }.
// All four sections are intra-iteration INDEPENDENT (softmax lags QK by one tile):
// compiler can interleave MFMA || VALU || trans, breaking the per-tile phase convoy
// (QK->softmax->PV serial chain) diagnosed from R5/R8. Buffer lifetimes:
// V slots live {kt+1,kt,kt-1,kt-2} = 4 distinct mod 4; K(kt+1) overwrites K(kt-1)
// (QK done prev iter, pre-barrier); pp RAW/WAR is register-ordered (PV before
// softmax in program order). S_cur/S_prev swapped via 2-unrolled pairs (static regs).
__global__ __launch_bounds__(256, 2) void flash_kernel(
    const u16* __restrict__ Q, const u16* __restrict__ K, const u16* __restrict__ Vt,
    const float* __restrict__ mask2, float* __restrict__ out) {
  __shared__ char smem[49152];  // K: 2 slots @ k*8192; V: 4 slots @ 16384 + v*8192
  int tid = threadIdx.x, wave = tid >> 6;
  int lane = tid & 63;
  int quad = lane >> 4, l16 = lane & 15;
  int bh = blockIdx.y, b = bh >> 4, h = bh & 15;
  int qw = blockIdx.x * 128 + wave * 32;
  const float* m2row = mask2 + b * S_;
  const u16* Kbase = K + (size_t)bh * S_ * D_;
  const u16* Vbase = Vt + (size_t)bh * D_ * S_;

  bf16x8 qfrag[2][2];
#pragma unroll
  for (int qb = 0; qb < 2; ++qb) {
    const u16* qp = Q + ((size_t)bh * S_ + qw + qb * 16 + l16) * D_ + quad * 8;
    qfrag[qb][0] = *(const bf16x8*)qp;
    qfrag[qb][1] = *(const bf16x8*)(qp + 32);
  }
  bf16x8 ones;
#pragma unroll
  for (int j = 0; j < 8; ++j) ones[j] = (short)0x3f80;  // bf16 1.0

  f32x4 o[2][4] = {};
  f32x4 lacc[2] = {};
  f32x4 sA[2][4], sB[2][4];
  bf16x8 pp[2][2];

#define ZERO_S(S)                                                 \
  _Pragma("unroll") for (int qb = 0; qb < 2; ++qb)                \
  _Pragma("unroll") for (int jt = 0; jt < 4; ++jt)                \
      S[qb][jt] = (f32x4){0.f, 0.f, 0.f, 0.f};

#define KSLOT(t) (smem + ((t) & 1) * 8192)
#define VSLOT(t) (smem + 16384 + ((t) & 3) * 8192)

  // prologue: stage tile 0; mv <- mask tile 0
  stage_kv2(Kbase, Vbase, KSLOT(0), VSLOT(0), 0, tid);
  float4 mv[4];
#pragma unroll
  for (int jt = 0; jt < 4; ++jt) mv[jt] = *(const float4*)(m2row + jt * 16 + quad * 4);

  // ---- kt = 0 (peel: QK only) ----
  __syncthreads();
  stage_kv2(Kbase, Vbase, KSLOT(1), VSLOT(1), 64, tid);
  ZERO_S(sB)
  __builtin_amdgcn_s_setprio(1);
  qk_step(KSLOT(0), qfrag, quad, l16, sB);  // s(0) -> sB
  __builtin_amdgcn_s_setprio(0);

  // ---- kt = 1 (peel: QK + softmax(0), no PV) ----
  __syncthreads();
  stage_kv2(Kbase, Vbase, KSLOT(2), VSLOT(2), 128, tid);
  ZERO_S(sA)
  __builtin_amdgcn_s_setprio(1);
  qk_step(KSLOT(1), qfrag, quad, l16, sA);  // s(1) -> sA
  __builtin_amdgcn_s_setprio(0);
  softmax_pack(sB, mv, pp);  // pp(0)
#pragma unroll
  for (int jt = 0; jt < 4; ++jt)
    mv[jt] = *(const float4*)(m2row + 64 + jt * 16 + quad * 4);  // mask tile 1

  // ---- steady: kt = 2..31 as 15 unrolled pairs (even -> sB, odd -> sA) ----
#define FLASH_BODY(kt, CUR, PREV)                                                  \
  {                                                                                \
    __syncthreads();                                                               \
    if ((kt) < 31)                                                                 \
      stage_kv2(Kbase, Vbase, KSLOT((kt) + 1), VSLOT((kt) + 1), ((kt) + 1) * 64,   \
                tid);                                                              \
    __builtin_amdgcn_s_setprio(1);                                                 \
    pv_step(pp, VSLOT((kt) - 2), quad, l16, ones, o, lacc); /* PV(kt-2) */         \
    ZERO_S(CUR)                                                                    \
    qk_step(KSLOT(kt), qfrag, quad, l16, CUR); /* s(kt) */                         \
    __builtin_amdgcn_s_setprio(0);                                                 \
    softmax_pack(PREV, mv, pp); /* pp(kt-1) */                                     \
    _Pragma("unroll") for (int jt = 0; jt < 4; ++jt)                               \
        mv[jt] = *(const float4*)(m2row + (kt) * 64 + jt * 16 + quad * 4);         \
  }

  for (int j = 0; j < 15; ++j) {
    int kt0 = 2 * j + 2;
    FLASH_BODY(kt0, sB, sA)      // even kt: QK -> sB, softmax(sA = s(kt-1))
    FLASH_BODY(kt0 + 1, sA, sB)  // odd kt:  QK -> sA, softmax(sB = s(kt-1))
  }
#undef FLASH_BODY

  // ---- drain: PV(30); softmax(31); PV(31) ----
  pv_step(pp, VSLOT(30), quad, l16, ones, o, lacc);  // pp(30) from kt=31 body
  softmax_pack(sA, mv, pp);                          // pp(31); mv holds mask tile 31
  pv_step(pp, VSLOT(31), quad, l16, ones, o, lacc);

#undef ZERO_S
#undef KSLOT
#undef VSLOT

  // epilogue: lacc[qb][r] holds the full row-sum for q = qw + qb*16 + quad*4 + r
  float inv[2][4];
#pragma unroll
  for (int qb = 0; qb < 2; ++qb)
#pragma unroll
    for (int r = 0; r < 4; ++r) inv[qb][r] = 1.0f / lacc[qb][r];
#pragma unroll
  for (int qb = 0; qb < 2; ++qb)
#pragma unroll
    for (int jd = 0; jd < 4; ++jd) {
#pragma unroll
      for (int r = 0; r < 4; ++r) {
        int d = jd * 16 + l16;
        int q = qw + qb * 16 + quad * 4 + r;
        out[(((size_t)b * S_ + q) * H_ + h) * D_ + d] = o[qb][jd][r] * inv[qb][r];
      }
    }
}

extern "C" void kernel_launch(void* const* d_in, const int* in_sizes, int n_in,
                              void* d_out, int out_size, void* d_ws, size_t ws_size,
                              hipStream_t stream) {
  const float* hid = (const float*)d_in[0];
  const float* mask = (const float*)d_in[1];
  const float* Wq = (const float*)d_in[2];
  const float* Wk = (const float*)d_in[3];
  const float* Wv = (const float*)d_in[4];
  float* out = (float*)d_out;
  char* ws = (char*)d_ws;

  u16* Xbf = (u16*)ws;                              // 8 MB
  u16* Wqb = (u16*)(ws + (8u << 20));               // 2 MB
  u16* Wkb = (u16*)(ws + (10u << 20));              // 2 MB
  u16* Wvb = (u16*)(ws + (12u << 20));              // 2 MB
  u16* Qb = (u16*)(ws + (14u << 20));               // 8 MB (BH,S,D)
  u16* Kb = (u16*)(ws + (22u << 20));               // 8 MB (BH,S,D)
  u16* Vtb = (u16*)(ws + (30u << 20));              // 8 MB (BH,D,S)
  float* cos_t = (float*)(ws + (38u << 20));        // 256 KB
  float* sin_t = (float*)(ws + (38u << 20) + (256u << 10));
  float* mask2 = (float*)(ws + (38u << 20) + (512u << 10));  // 16 KB

  prep_kernel<<<7440, 256, 0, stream>>>(hid, Wq, Wk, Wv, mask, Xbf, Wqb, Wkb, Wvb,
                                        cos_t, sin_t, mask2);
  qkv_gemm_kernel<<<dim3(8, 32), 512, 0, stream>>>(Xbf, Wqb, Wkb, Wvb, cos_t, sin_t,
                                                   Qb, Kb, Vtb);
  flash_kernel<<<dim3(16, 32), 256, 0, stream>>>(Qb, Kb, Vtb, mask2, out);
}

// Round 10
// 157.469 us; speedup vs baseline: 1.5025x; 1.0111x over previous
//
#include <hip/hip_runtime.h>
#include <stdint.h>

typedef unsigned short u16;
typedef short bf16x8 __attribute__((ext_vector_type(8)));
typedef float f32x4 __attribute__((ext_vector_type(4)));

#define S_ 2048
#define HID_ 1024
#define H_ 16
#define D_ 64

#define LOG2E 1.4426950408889634f
#define SCALE_LOG2 0.18033688011112042f   /* 0.125 * log2(e) */
#define MAXC_LOG2 11.541560327111707f     /* 8 * log2(e) */

__device__ __forceinline__ u16 f2bf(float f) {
  uint32_t x = __builtin_bit_cast(uint32_t, f);
  uint32_t r = (x + 0x7fffu + ((x >> 16) & 1u)) >> 16;
  return (u16)r;
}
__device__ __forceinline__ uint32_t packbf2(float a, float b) {
  return (uint32_t)f2bf(a) | ((uint32_t)f2bf(b) << 16);
}
// truncating pack: low16 = bf16(a), high16 = bf16(b), one v_perm_b32
__device__ __forceinline__ uint32_t permpack(float a, float b) {
  return __builtin_amdgcn_perm(__builtin_bit_cast(uint32_t, b),
                               __builtin_bit_cast(uint32_t, a), 0x07060302u);
}

__device__ __forceinline__ void gl2lds16(const void* g, void* l) {
  __builtin_amdgcn_global_load_lds(
      (const __attribute__((address_space(1))) unsigned int*)g,
      (__attribute__((address_space(3))) unsigned int*)l, 16, 0, 0);
}

// ------------- prep: converts + RoPE tables + mask2, one kernel -------------
#define NX_ (1 << 20)
#define NW_ (1 << 18)
#define NROPE_ 65536
__global__ void prep_kernel(const float* __restrict__ X, const float* __restrict__ Wq,
                            const float* __restrict__ Wk, const float* __restrict__ Wv,
                            const float* __restrict__ mask, u16* __restrict__ Xb,
                            u16* __restrict__ Wqb, u16* __restrict__ Wkb,
                            u16* __restrict__ Wvb, float* __restrict__ cos_t,
                            float* __restrict__ sin_t, float* __restrict__ mask2) {
  int i = blockIdx.x * 256 + threadIdx.x;
  if (i < NX_ + 3 * NW_) {
    const float* src;
    u16* dst;
    int off;
    if (i < NX_) {
      src = X; dst = Xb; off = i;
    } else if (i < NX_ + NW_) {
      src = Wq; dst = Wqb; off = i - NX_;
    } else if (i < NX_ + 2 * NW_) {
      src = Wk; dst = Wkb; off = i - NX_ - NW_;
    } else {
      src = Wv; dst = Wvb; off = i - NX_ - 2 * NW_;
    }
    float4 v = ((const float4*)src)[off];
    uint2 packed;
    packed.x = packbf2(v.x, v.y);
    packed.y = packbf2(v.z, v.w);
    ((uint2*)dst)[off] = packed;
  } else if (i < NX_ + 3 * NW_ + NROPE_) {
    int t = i - (NX_ + 3 * NW_);  // 65536 = 2048*32
    int s = t >> 5, j = t & 31;
    float invf = powf(10000.0f, -(float)j * (1.0f / 32.0f));
    float ang = (float)s * invf;
    cos_t[t] = cosf(ang);
    sin_t[t] = sinf(ang);
  } else {
    int t = i - (NX_ + 3 * NW_ + NROPE_);  // 4096 = 2*2048
    mask2[t] = fmaf(mask[t], LOG2E, -MAXC_LOG2);
  }
}

// ---------------- Fused QKV GEMM (R6 proven): one block, Q+K+V ----------------
// grid (8, 32) = 256 blocks = 1/CU, zero dispatch tail. 512 threads (8 waves 2m x 4n).
// A staged ONCE per K-step, shared by all 3 B matrices. LDS 128 KB dbuf,
// stage-before-compute, 1 barrier/K-step.
__global__ __launch_bounds__(512, 2) void qkv_gemm_kernel(
    const u16* __restrict__ X, const u16* __restrict__ Wq, const u16* __restrict__ Wk,
    const u16* __restrict__ Wv, const float* __restrict__ cos_t,
    const float* __restrict__ sin_t, u16* __restrict__ Q, u16* __restrict__ K,
    u16* __restrict__ Vt) {
  __shared__ char smem[131072];
  int tid = threadIdx.x;
  int lane = tid & 63, wave = tid >> 6;
  int wm = wave >> 2, wn = wave & 3;
  int quad = lane >> 4, l16 = lane & 15;
  int nbase = blockIdx.x * 128;
  int mbase = blockIdx.y * 128;

#define STAGE_ALL(k0, buf)                                                        \
  {                                                                               \
    _Pragma("unroll") for (int it = 0; it < 8; ++it) {                            \
      int j = (it & 1) * 512 + tid;                                               \
      int r = j >> 3, gs = j & 7, gsrc = gs ^ (r & 7);                            \
      const u16* src; int rb;                                                     \
      if ((it >> 1) == 0)      { src = X;  rb = mbase + r; }                      \
      else if ((it >> 1) == 1) { src = Wq; rb = nbase + r; }                      \
      else if ((it >> 1) == 2) { src = Wk; rb = nbase + r; }                      \
      else                     { src = Wv; rb = nbase + r; }                      \
      gl2lds16(src + (size_t)rb * HID_ + (k0) + gsrc * 8,                         \
               (buf) + (it >> 1) * 16384 + j * 16);                               \
    }                                                                             \
  }

  STAGE_ALL(0, smem)  // tile 0 -> buf 0

  f32x4 acc[3][4][2] = {};  // [which][i4 m-block][j2 n-pair]

  for (int kk = 0; kk < 16; ++kk) {
    const char* buf = smem + (kk & 1) * 65536;
    __syncthreads();  // staging of tile kk complete

    if (kk < 15)  // stage tile kk+1 into other buffer (its reads finished pre-barrier)
      STAGE_ALL((kk + 1) * 64, smem + ((kk + 1) & 1) * 65536)

#pragma unroll
    for (int kh = 0; kh < 2; ++kh) {
      bf16x8 afrag[4];
#pragma unroll
      for (int i4 = 0; i4 < 4; ++i4) {
        int r = wm * 64 + i4 * 16 + l16;
        int L = r * 8 + ((kh * 4 + quad) ^ (r & 7));
        afrag[i4] = *(const bf16x8*)(buf + L * 16);
      }
#pragma unroll
      for (int w = 0; w < 3; ++w) {
        const char* Bs = buf + 16384 + w * 16384;
        bf16x8 bfrag[2];
#pragma unroll
        for (int j2 = 0; j2 < 2; ++j2) {
          int r = (wn >> 1) * 64 + (wn & 1) * 16 + j2 * 32 + l16;
          int L = r * 8 + ((kh * 4 + quad) ^ (r & 7));
          bfrag[j2] = *(const bf16x8*)(Bs + L * 16);
        }
        if (w == 2) {
#pragma unroll
          for (int i4 = 0; i4 < 4; ++i4)
#pragma unroll
            for (int j2 = 0; j2 < 2; ++j2)
              acc[2][i4][j2] = __builtin_amdgcn_mfma_f32_16x16x32_bf16(
                  afrag[i4], bfrag[j2], acc[2][i4][j2], 0, 0, 0);
        } else if (w == 1) {
#pragma unroll
          for (int i4 = 0; i4 < 4; ++i4)
#pragma unroll
            for (int j2 = 0; j2 < 2; ++j2)
              acc[1][i4][j2] = __builtin_amdgcn_mfma_f32_16x16x32_bf16(
                  bfrag[j2], afrag[i4], acc[1][i4][j2], 0, 0, 0);
        } else {
#pragma unroll
          for (int i4 = 0; i4 < 4; ++i4)
#pragma unroll
            for (int j2 = 0; j2 < 2; ++j2)
              acc[0][i4][j2] = __builtin_amdgcn_mfma_f32_16x16x32_bf16(
                  bfrag[j2], afrag[i4], acc[0][i4][j2], 0, 0, 0);
        }
      }
    }
  }
#undef STAGE_ALL

  // ---- V epilogue (w=2, non-swapped): C row = m (quad*4+reg), col = n (l16) ----
#pragma unroll
  for (int i4 = 0; i4 < 4; ++i4)
#pragma unroll
    for (int j2 = 0; j2 < 2; ++j2) {
      int m = mbase + wm * 64 + i4 * 16 + quad * 4;
      int n = nbase + (wn >> 1) * 64 + (wn & 1) * 16 + j2 * 32 + l16;
      int b = m >> 11, s0 = m & 2047;
      int h = n >> 6, d = n & 63;
      uint2 pk;
      pk.x = packbf2(acc[2][i4][j2][0], acc[2][i4][j2][1]);
      pk.y = packbf2(acc[2][i4][j2][2], acc[2][i4][j2][3]);
      *(uint2*)(Vt + (((size_t)(b * H_ + h)) * D_ + d) * S_ + s0) = pk;
    }

  // ---- Q/K epilogue (swapped): C row = n (quad*4+reg), col = m (l16); fused RoPE ----
#pragma unroll
  for (int w = 0; w < 2; ++w) {
    u16* dst = (w == 0) ? Q : K;
#pragma unroll
    for (int i4 = 0; i4 < 4; ++i4) {
      int m = mbase + wm * 64 + i4 * 16 + l16;
      int n1 = nbase + (wn >> 1) * 64 + (wn & 1) * 16 + quad * 4;
      int b = m >> 11, s = m & 2047;
      int h = n1 >> 6, d1 = n1 & 63;  // d1 in [0,32), multiple of 4
      float4 c4 = *(const float4*)(cos_t + s * 32 + d1);
      float4 s4 = *(const float4*)(sin_t + s * 32 + d1);
      float y1[4], y2[4];
#pragma unroll
      for (int r = 0; r < 4; ++r) {
        float cr = ((const float*)&c4)[r], sr = ((const float*)&s4)[r];
        float x1 = acc[w][i4][0][r], x2 = acc[w][i4][1][r];
        y1[r] = x1 * cr - x2 * sr;
        y2[r] = x2 * cr + x1 * sr;
      }
      size_t base = ((size_t)(b * H_ + h) * S_ + s) * D_;
      uint2 p1, p2;
      p1.x = packbf2(y1[0], y1[1]);
      p1.y = packbf2(y1[2], y1[3]);
      p2.x = packbf2(y2[0], y2[1]);
      p2.y = packbf2(y2[2], y2[3]);
      *(uint2*)(dst + base + d1) = p1;
      *(uint2*)(dst + base + d1 + 32) = p2;
    }
  }
}

// ---------- flash helpers ----------
// fixed-max softmax (exp2 + truncating perm-pack), then IN-REGISTER q<->key
// transpose via permlane swaps (R4 proven, bit-identical P routing).
__device__ __forceinline__ void softmax_pack(const f32x4 (*s)[4], const float4* mv,
                                             bf16x8 (*pp)[2]) {
#pragma unroll
  for (int qb = 0; qb < 2; ++qb) {
    uint32_t a[4][2];
#pragma unroll
    for (int jt = 0; jt < 4; ++jt) {
      float pf[4];
#pragma unroll
      for (int r = 0; r < 4; ++r) {
        float mvr = ((const float*)&mv[jt])[r];
        pf[r] = __builtin_amdgcn_exp2f(fmaf(s[qb][jt][r], SCALE_LOG2, mvr));
      }
      a[jt][0] = permpack(pf[0], pf[1]);
      a[jt][1] = permpack(pf[2], pf[3]);
    }
#pragma unroll
    for (int kh = 0; kh < 2; ++kh) {
      uint32_t tt[4];
#pragma unroll
      for (int i = 0; i < 2; ++i) {
        auto r1 = __builtin_amdgcn_permlane32_swap(a[2 * kh][i], a[2 * kh + 1][i],
                                                   false, false);
        auto r2 = __builtin_amdgcn_permlane16_swap(r1[0], r1[1], false, false);
        tt[i] = r2[0];      // T[kh][0+i]
        tt[2 + i] = r2[1];  // T[kh][2+i]
      }
      union { uint32_t u[4]; bf16x8 v; } cv;
      cv.u[0] = tt[0]; cv.u[1] = tt[1]; cv.u[2] = tt[2]; cv.u[3] = tt[3];
      pp[qb][kh] = cv.v;
    }
  }
}

// ---------------- Flash attention: R6 structure, issue-thinned ----------------
// grid (16, 32), 2 blocks/CU, 4 waves x 32 q, 64-key tiles, K/V triple-buffer
// (48 KB), P in registers, 1 barrier/tile. Changes vs R6 (semantics-preserving):
//  (1) steady loop unrolled x3 -> kt%3 compile-time -> every ds_read_b128 is
//      [lane-base + literal] off 2 persistent base VGPRs (LDS read offset
//      L*16 = jt*2048 + l16*128 + ((kh*4+quad)^(l16&7))*16 is tile-invariant;
//      buffer base fits the 16-bit ds offset imm). Steady addr-VALU ~ 0.
//  (2) zero-C QK: first kh MFMA takes a persistent zero reg as C-in,
//      eliminating 32 v_movs/tile of s-zeroing.
//  (3) pointer-advanced staging/mask bases (no per-tile multiplies).
// Rationale: R5 (2x occupancy, 0 gain) + invariant per-SIMD busy% => per-SIMD
// issue-bound; dynamic instruction count is the lever.
__global__ __launch_bounds__(256, 2) void flash_kernel(
    const u16* __restrict__ Q, const u16* __restrict__ K, const u16* __restrict__ Vt,
    const float* __restrict__ mask2, float* __restrict__ out) {
  __shared__ char smem[49152];  // slot t%3 @ t*16384: K @ +0, V @ +8192
  int tid = threadIdx.x, wave = tid >> 6;
  int lane = tid & 63;
  int quad = lane >> 4, l16 = lane & 15;
  int bh = blockIdx.y, b = bh >> 4, h = bh & 15;
  int qw = blockIdx.x * 128 + wave * 32;
  const u16* Kbase = K + (size_t)bh * S_ * D_;
  const u16* Vbase = Vt + (size_t)bh * D_ * S_;

  // tile-invariant per-lane LDS read bases (kh = 0 / 1)
  char* bk0 = smem + l16 * 128 + ((quad ^ (l16 & 7)) * 16);
  char* bk1 = smem + l16 * 128 + (((4 + quad) ^ (l16 & 7)) * 16);

  // staging lane offsets (r = tid>>3 plus +32 for second half; r&7 invariant)
  int r0 = tid >> 3, gs = tid & 7, gsrc = gs ^ (r0 & 7);
  size_t koff = (size_t)r0 * D_ + gsrc * 8;
  size_t voff = (size_t)r0 * S_ + gsrc * 8;
  const u16* kg = Kbase;  // advances 64*D_ per staged tile
  const u16* vg = Vbase;  // advances 64 per staged tile
  const float* mq = mask2 + b * S_;  // advances 64 per consumed mask tile

#define STAGE(SB)                                                      \
  {                                                                    \
    gl2lds16(kg + koff, smem + (SB) * 16384 + tid * 16);               \
    gl2lds16(kg + koff + 32 * D_, smem + (SB) * 16384 + 4096 + tid * 16); \
    gl2lds16(vg + voff, smem + (SB) * 16384 + 8192 + tid * 16);        \
    gl2lds16(vg + voff + 32 * S_, smem + (SB) * 16384 + 12288 + tid * 16); \
    kg += 64 * D_;                                                     \
    vg += 64;                                                          \
  }

#define MVLOAD                                                         \
  {                                                                    \
    _Pragma("unroll") for (int jt = 0; jt < 4; ++jt)                   \
        mv[jt] = *(const float4*)(mq + jt * 16 + quad * 4);            \
    mq += 64;                                                          \
  }

  // QK with zero-C first step: s = kf0*qf0 + 0; s += kf1*qf1  (== R6 semantics)
#define QK_Z(KOFF, s)                                                             \
  {                                                                               \
    _Pragma("unroll") for (int jt = 0; jt < 4; ++jt) {                            \
      bf16x8 kf0 = *(const bf16x8*)(bk0 + (KOFF) + jt * 2048);                    \
      bf16x8 kf1 = *(const bf16x8*)(bk1 + (KOFF) + jt * 2048);                    \
      s[0][jt] = __builtin_amdgcn_mfma_f32_16x16x32_bf16(kf0, qfrag[0][0], zc, 0, 0, 0); \
      s[0][jt] = __builtin_amdgcn_mfma_f32_16x16x32_bf16(kf1, qfrag[0][1], s[0][jt], 0, 0, 0); \
      s[1][jt] = __builtin_amdgcn_mfma_f32_16x16x32_bf16(kf0, qfrag[1][0], zc, 0, 0, 0); \
      s[1][jt] = __builtin_amdgcn_mfma_f32_16x16x32_bf16(kf1, qfrag[1][1], s[1][jt], 0, 0, 0); \
    }                                                                             \
  }

#define PV(VOFF)                                                                  \
  {                                                                               \
    lacc[0] = __builtin_amdgcn_mfma_f32_16x16x32_bf16(pp[0][0], ones, lacc[0], 0, 0, 0); \
    lacc[0] = __builtin_amdgcn_mfma_f32_16x16x32_bf16(pp[0][1], ones, lacc[0], 0, 0, 0); \
    lacc[1] = __builtin_amdgcn_mfma_f32_16x16x32_bf16(pp[1][0], ones, lacc[1], 0, 0, 0); \
    lacc[1] = __builtin_amdgcn_mfma_f32_16x16x32_bf16(pp[1][1], ones, lacc[1], 0, 0, 0); \
    _Pragma("unroll") for (int jd = 0; jd < 4; ++jd) {                            \
      bf16x8 vf0 = *(const bf16x8*)(bk0 + (VOFF) + jd * 2048);                    \
      bf16x8 vf1 = *(const bf16x8*)(bk1 + (VOFF) + jd * 2048);                    \
      o[0][jd] = __builtin_amdgcn_mfma_f32_16x16x32_bf16(pp[0][0], vf0, o[0][jd], 0, 0, 0); \
      o[0][jd] = __builtin_amdgcn_mfma_f32_16x16x32_bf16(pp[0][1], vf1, o[0][jd], 0, 0, 0); \
      o[1][jd] = __builtin_amdgcn_mfma_f32_16x16x32_bf16(pp[1][0], vf0, o[1][jd], 0, 0, 0); \
      o[1][jd] = __builtin_amdgcn_mfma_f32_16x16x32_bf16(pp[1][1], vf1, o[1][jd], 0, 0, 0); \
    }                                                                             \
  }

  // steady body for kt with M = kt%3 (compile-time): sync; stage(kt+1);
  // PV(kt-1) [slot (M+2)%3]; QK(kt) [slot M]; softmax(kt)->pp; mv <- kt+1.
#define BODY(M)                                                        \
  {                                                                    \
    __syncthreads();                                                   \
    STAGE(((M) + 1) % 3)                                               \
    __builtin_amdgcn_s_setprio(1);                                     \
    PV((((M) + 2) % 3) * 16384 + 8192)                                 \
    f32x4 s[2][4];                                                     \
    QK_Z((M) * 16384, s)                                               \
    __builtin_amdgcn_s_setprio(0);                                     \
    softmax_pack(s, mv, pp);                                           \
    MVLOAD                                                             \
  }

  bf16x8 qfrag[2][2];
#pragma unroll
  for (int qb = 0; qb < 2; ++qb) {
    const u16* qp = Q + ((size_t)bh * S_ + qw + qb * 16 + l16) * D_ + quad * 8;
    qfrag[qb][0] = *(const bf16x8*)qp;
    qfrag[qb][1] = *(const bf16x8*)(qp + 32);
  }
  bf16x8 ones;
#pragma unroll
  for (int j = 0; j < 8; ++j) ones[j] = (short)0x3f80;  // bf16 1.0
  const f32x4 zc = {0.f, 0.f, 0.f, 0.f};

  f32x4 o[2][4] = {};
  f32x4 lacc[2] = {};
  bf16x8 pp[2][2];  // P(kt) fragments, consumed by PV in iter kt+1
  float4 mv[4];

  // prologue: stage tile 0 (kg/vg advance to tile 1); mv <- tile 0 (mq -> tile 1)
  STAGE(0)
  MVLOAD

  // ---- kt = 0 (peeled: no PV) ----
  {
    __syncthreads();  // tile 0 staged
    STAGE(1)          // tile 1
    f32x4 s[2][4];
    __builtin_amdgcn_s_setprio(1);
    QK_Z(0, s)
    __builtin_amdgcn_s_setprio(0);
    softmax_pack(s, mv, pp);  // pp(0)
    MVLOAD                     // mv <- tile 1
  }

  // ---- steady: kt = 1..30 = 10 x {1,2,0} (M = kt%3 compile-time) ----
  for (int j = 0; j < 10; ++j) {
    BODY(1)
    BODY(2)
    BODY(0)
  }

  // ---- kt = 31 (peeled: no stage, no mask advance; M = 31%3 = 1) ----
  {
    __syncthreads();
    __builtin_amdgcn_s_setprio(1);
    PV(0 * 16384 + 8192)  // PV(30), V slot 30%3 = 0
    f32x4 s[2][4];
    QK_Z(1 * 16384, s)    // K(31) in slot 1
    __builtin_amdgcn_s_setprio(0);
    softmax_pack(s, mv, pp);  // pp(31); mv holds mask tile 31
  }

  // drain: PV(31), V slot 31%3 = 1
  PV(1 * 16384 + 8192)

#undef STAGE
#undef MVLOAD
#undef QK_Z
#undef PV
#undef BODY

  // epilogue: lacc[qb][r] holds the full row-sum for q = qw + qb*16 + quad*4 + r
  float inv[2][4];
#pragma unroll
  for (int qb = 0; qb < 2; ++qb)
#pragma unroll
    for (int r = 0; r < 4; ++r) inv[qb][r] = 1.0f / lacc[qb][r];
#pragma unroll
  for (int qb = 0; qb < 2; ++qb)
#pragma unroll
    for (int jd = 0; jd < 4; ++jd) {
#pragma unroll
      for (int r = 0; r < 4; ++r) {
        int d = jd * 16 + l16;
        int q = qw + qb * 16 + quad * 4 + r;
        out[(((size_t)b * S_ + q) * H_ + h) * D_ + d] = o[qb][jd][r] * inv[qb][r];
      }
    }
}

extern "C" void kernel_launch(void* const* d_in, const int* in_sizes, int n_in,
                              void* d_out, int out_size, void* d_ws, size_t ws_size,
                              hipStream_t stream) {
  const float* hid = (const float*)d_in[0];
  const float* mask = (const float*)d_in[1];
  const float* Wq = (const float*)d_in[2];
  const float* Wk = (const float*)d_in[3];
  const float* Wv = (const float*)d_in[4];
  float* out = (float*)d_out;
  char* ws = (char*)d_ws;

  u16* Xbf = (u16*)ws;                              // 8 MB
  u16* Wqb = (u16*)(ws + (8u << 20));               // 2 MB
  u16* Wkb = (u16*)(ws + (10u << 20));              // 2 MB
  u16* Wvb = (u16*)(ws + (12u << 20));              // 2 MB
  u16* Qb = (u16*)(ws + (14u << 20));               // 8 MB (BH,S,D)
  u16* Kb = (u16*)(ws + (22u << 20));               // 8 MB (BH,S,D)
  u16* Vtb = (u16*)(ws + (30u << 20));              // 8 MB (BH,D,S)
  float* cos_t = (float*)(ws + (38u << 20));        // 256 KB
  float* sin_t = (float*)(ws + (38u << 20) + (256u << 10));
  float* mask2 = (float*)(ws + (38u << 20) + (512u << 10));  // 16 KB

  prep_kernel<<<7440, 256, 0, stream>>>(hid, Wq, Wk, Wv, mask, Xbf, Wqb, Wkb, Wvb,
                                        cos_t, sin_t, mask2);
  qkv_gemm_kernel<<<dim3(8, 32), 512, 0, stream>>>(Xbf, Wqb, Wkb, Wvb, cos_t, sin_t,
                                                   Qb, Kb, Vtb);
  flash_kernel<<<dim3(16, 32), 256, 0, stream>>>(Qb, Kb, Vtb, mask2, out);
}